// Round 10
// baseline (350.199 us; speedup 1.0000x reference)
//
#include <hip/hip_runtime.h>
#include <hip/hip_bf16.h>

#define N_NODES 50000
#define N_EDGES 1600000
#define N_GRAPHS 64

// bucket sort geometry
#define NBKT 250          // buckets of 200 nodes each
#define BKT_NODES 200
#define BKT_CAP 7168      // mean 6400, sigma ~80; +9.6 sigma; guard-checked
#define CHUNK 4096        // edges per k_front bucket block
#define NBB 391           // ceil(1600000/4096)
#define NCVX 6250         // x-convert blocks
#define NCVW 256          // weight-convert blocks
#define ZROW N_NODES      // zero-row index for gather padding

typedef short bf16x8 __attribute__((ext_vector_type(8)));
typedef float f32x4 __attribute__((ext_vector_type(4)));
typedef float f32x2 __attribute__((ext_vector_type(2)));

__device__ __forceinline__ float bf_lo(unsigned int u) { return __uint_as_float(u << 16); }
__device__ __forceinline__ float bf_hi(unsigned int u) { return __uint_as_float(u & 0xffff0000u); }
__device__ __forceinline__ unsigned short f2bf(float f) {
    unsigned int u = __float_as_uint(f);
    u = (u + 0x7fffu + ((u >> 16) & 1u)) >> 16;
    return (unsigned short)u;
}
__device__ __forceinline__ unsigned int pack2bf(float a, float b) {
    return (unsigned int)f2bf(a) | ((unsigned int)f2bf(b) << 16);
}
__device__ __forceinline__ unsigned int pack4fp8(float a, float b, float c, float d) {
    unsigned int q = __builtin_amdgcn_cvt_pk_fp8_f32(a, b, 0, false);
    q = __builtin_amdgcn_cvt_pk_fp8_f32(c, d, q, true);
    return q;
}
__device__ __forceinline__ void load_lds16(const void* g, void* l) {
    __builtin_amdgcn_global_load_lds(
        (const __attribute__((address_space(1))) void*)g,
        (__attribute__((address_space(3))) void*)l, 16, 0, 0);
}

// ---------------------------------------------------------------------------
// k_front: fused {edge bucketing | x->bf16+fp8 convert | weight converts}
// First convert block also writes the ZROW zero rows (replaces 3 memsets).
// ---------------------------------------------------------------------------
__global__ __launch_bounds__(256) void k_front(
    const int* __restrict__ src, const int* __restrict__ dst,
    unsigned int* __restrict__ bucketed, int* __restrict__ gcnt,
    const float* __restrict__ x, unsigned short* __restrict__ A1x,
    unsigned char* __restrict__ x8, unsigned char* __restrict__ h18,
    unsigned char* __restrict__ t3l8,
    const float* __restrict__ W1l, const float* __restrict__ W1r,
    const float* __restrict__ W2l, const float* __restrict__ W2r,
    const float* __restrict__ W3l, const float* __restrict__ W3r,
    unsigned short* __restrict__ Wp1, unsigned short* __restrict__ Wp2,
    unsigned short* __restrict__ Wp3) {
    const int blk = blockIdx.x;
    const int t = threadIdx.x;

    if (blk < NBB) {
        __shared__ int lcnt[256];
        __shared__ int sc[256];
        __shared__ int lscan[256];
        __shared__ int gb[256];
        __shared__ unsigned int grouped[CHUNK];

        const int base = blk * CHUNK;
        const int ccnt = min(CHUNK, N_EDGES - base);
        lcnt[t] = 0;
        __syncthreads();

        unsigned int pk[CHUNK / 256];
        int rk[CHUNK / 256];
#pragma unroll
        for (int r = 0; r < CHUNK / 256; ++r) {
            int j = r * 256 + t;
            rk[r] = -1;
            if (j < ccnt) {
                int i = base + j;
                int s = src[i];
                int d = dst[i];
                int b = d / BKT_NODES;
                int dl = d - b * BKT_NODES;
                pk[r] = (unsigned int)s | ((unsigned int)dl << 16) | ((unsigned int)b << 24);
                rk[r] = atomicAdd(&lcnt[b], 1);
            }
        }
        __syncthreads();
        sc[t] = lcnt[t];
        __syncthreads();
        for (int off = 1; off < 256; off <<= 1) {
            int v = (t >= off) ? sc[t - off] : 0;
            __syncthreads();
            sc[t] += v;
            __syncthreads();
        }
        lscan[t] = sc[t] - lcnt[t];
        if (t < NBKT && lcnt[t] > 0) gb[t] = atomicAdd(&gcnt[t], lcnt[t]);
        __syncthreads();
#pragma unroll
        for (int r = 0; r < CHUNK / 256; ++r) {
            if (rk[r] >= 0) {
                int b = pk[r] >> 24;
                grouped[lscan[b] + rk[r]] = pk[r];
            }
        }
        __syncthreads();
#pragma unroll
        for (int r = 0; r < CHUNK / 256; ++r) {
            int j = r * 256 + t;
            if (j < ccnt) {
                unsigned int v = grouped[j];
                int b = v >> 24;
                int pos = gb[b] + (j - lscan[b]);
                if (pos < BKT_CAP) bucketed[b * BKT_CAP + pos] = v;
            }
        }
    } else if (blk < NBB + NCVX) {
        // ---- x -> bf16 (A1 right half, stride 256) + fp8 ([.][128]) ----
        int i = (blk - NBB) * 256 + t;  // exactly 1.6M units of 4 floats
        int r = i >> 5;
        int f4 = (i & 31) << 2;
        float4 v = *(const float4*)&x[(size_t)r * 128 + f4];
        uint2 o;
        o.x = pack2bf(v.x, v.y);
        o.y = pack2bf(v.z, v.w);
        *(uint2*)&A1x[(size_t)r * 256 + f4] = o;
        *(unsigned int*)&x8[(size_t)r * 128 + f4] = pack4fp8(v.x, v.y, v.z, v.w);
        // zero rows for gather padding (once)
        if (blk == NBB && t < 32) {
            uint4 z = make_uint4(0, 0, 0, 0);
            if (t < 8) *(uint4*)&x8[(size_t)ZROW * 128 + t * 16] = z;
            else if (t < 24) *(uint4*)&h18[(size_t)ZROW * 256 + (t - 8) * 16] = z;
            else *(uint4*)&t3l8[(size_t)ZROW * 128 + (t - 24) * 16] = z;
        }
    } else {
        // ---- all 6 weight matrices -> packed bf16 ----
        int i = (blk - NBB - NCVX) * 256 + t;  // 0..65535
        const float* srcp;
        unsigned short* dstp;
        int sf4, dstride;
        if (i < 16384) {
            int h = i >> 13;
            i &= 8191;
            srcp = h ? W1r : W1l;
            dstp = Wp1 + (h ? 128 : 0);
            sf4 = 32; dstride = 256;
        } else if (i < 49152) {
            int j = i - 16384;
            int h = j >> 14;
            i = j & 16383;
            srcp = h ? W2r : W2l;
            dstp = Wp2 + (h ? 256 : 0);
            sf4 = 64; dstride = 512;
        } else {
            int j = i - 49152;
            int h = j >> 13;
            i = j & 8191;
            srcp = h ? W3r : W3l;
            dstp = Wp3 + (h ? 128 * 256 : 0);
            sf4 = 64; dstride = 256;
        }
        int r = i / sf4;
        int f4 = (i % sf4) * 4;
        float4 v = *(const float4*)&srcp[(size_t)r * (sf4 * 4) + f4];
        uint2 o;
        o.x = pack2bf(v.x, v.y);
        o.y = pack2bf(v.z, v.w);
        *(uint2*)&dstp[(size_t)r * dstride + f4] = o;
    }
}

// ---------------------------------------------------------------------------
// k_place: one block (512 thr) per bucket. Slack-scan (x4-rounded) of bucket
// counts -> x4-aligned global starts; LDS counting sort -> offs/deg + padded
// ssrc (segments padded to x4 with ZROW).
// ---------------------------------------------------------------------------
__global__ __launch_bounds__(512) void k_place(const unsigned int* __restrict__ bucketed,
                                               const int* __restrict__ gcnt,
                                               int* __restrict__ offs,
                                               unsigned short* __restrict__ deg,
                                               unsigned short* __restrict__ ssrc) {
    __shared__ unsigned int ent[BKT_CAP];
    __shared__ unsigned short rks[BKT_CAP];
    __shared__ int lcnt[256];
    __shared__ int sc[256];
    __shared__ int lofs[256];
    __shared__ int gs;

    const int b = blockIdx.x;
    const int t = threadIdx.x;

    // slack scan (inclusive) over x4-rounded per-bucket upper bounds
    if (t < 256) sc[t] = (t < NBKT) ? (((gcnt[t] + 3) & ~3) + 3 * BKT_NODES) : 0;
    __syncthreads();
    for (int off = 1; off < 256; off <<= 1) {
        int u = 0;
        if (t < 256 && t >= off) u = sc[t - off];
        __syncthreads();
        if (t < 256) sc[t] += u;
        __syncthreads();
    }
    if (t == 0) gs = (b == 0) ? 0 : sc[b - 1];
    if (t < 256) lcnt[t] = 0;
    __syncthreads();

    const int cnt = min(gcnt[b], BKT_CAP);
    const unsigned int* eg = bucketed + (size_t)b * BKT_CAP;
    for (int i = t; i < cnt; i += 512) {
        unsigned int v = eg[i];
        ent[i] = v;
        int dl = (v >> 16) & 0xFF;
        rks[i] = (unsigned short)atomicAdd(&lcnt[dl], 1);
    }
    __syncthreads();
    // padded exclusive scan of per-node counts
    int pc = 0;
    if (t < 256) {
        pc = (lcnt[t] + 3) & ~3;
        sc[t] = pc;
    }
    __syncthreads();
    for (int off = 1; off < 256; off <<= 1) {
        int u = 0;
        if (t < 256 && t >= off) u = sc[t - off];
        __syncthreads();
        if (t < 256) sc[t] += u;
        __syncthreads();
    }
    if (t < 256) lofs[t] = sc[t] - pc;
    __syncthreads();
    const int gstart = gs;
    if (t < BKT_NODES) {
        offs[b * BKT_NODES + t] = gstart + lofs[t];
        deg[b * BKT_NODES + t] = (unsigned short)lcnt[t];
    }
    for (int i = t; i < cnt; i += 512) {
        unsigned int v = ent[i];
        int dl = (v >> 16) & 0xFF;
        ssrc[gstart + lofs[dl] + (int)rks[i]] = (unsigned short)(v & 0xFFFF);
    }
    if (t < BKT_NODES) {
        int d = lcnt[t], pd = (d + 3) & ~3;
        int base = gstart + lofs[t];
        for (int j = d; j < pd; ++j) ssrc[base + j] = (unsigned short)ZROW;
    }
}

// ---------------------------------------------------------------------------
// fp8 gather-mean -> bf16. Padded x4 segments, x4-aligned starts, 2-deep
// register pipeline.
// ---------------------------------------------------------------------------
#define DEC_ADD(dw, base)                                             \
    {                                                                 \
        f32x2 lo_ = __builtin_amdgcn_cvt_pk_f32_fp8((dw), false);     \
        f32x2 hi_ = __builtin_amdgcn_cvt_pk_f32_fp8((dw), true);      \
        a[(base) + 0] += lo_.x;                                       \
        a[(base) + 1] += lo_.y;                                       \
        a[(base) + 2] += hi_.x;                                       \
        a[(base) + 3] += hi_.y;                                       \
    }
#define DEC_ADD4(v) { DEC_ADD((v).x, 0) DEC_ADD((v).y, 4) DEC_ADD((v).z, 8) DEC_ADD((v).w, 12) }

template <int F>
__global__ __launch_bounds__(256) void k_gather8(const unsigned char* __restrict__ in,
                                                 unsigned short* __restrict__ out,
                                                 int ostride,
                                                 const int* __restrict__ offs,
                                                 const unsigned short* __restrict__ deg,
                                                 const unsigned short* __restrict__ ssrc) {
    constexpr int TPN = F / 16;
    constexpr int NPB = 256 / TPN;
    int n = blockIdx.x * NPB + threadIdx.x / TPN;
    int f16 = (threadIdx.x % TPN) * 16;
    if (n >= N_NODES) return;
    int s0 = offs[n];
    int d = deg[n];
    int pd = (d + 3) & ~3;
    float a[16];
#pragma unroll
    for (int j = 0; j < 16; ++j) a[j] = 0.f;
    const unsigned char* inf = in + f16;
    if (pd > 0) {
        ushort4 es = *(const ushort4*)&ssrc[s0];
        uint4 c0 = *(const uint4*)&inf[(size_t)es.x * F];
        uint4 c1 = *(const uint4*)&inf[(size_t)es.y * F];
        uint4 c2 = *(const uint4*)&inf[(size_t)es.z * F];
        uint4 c3 = *(const uint4*)&inf[(size_t)es.w * F];
        for (int i = s0 + 4; i < s0 + pd; i += 4) {
            ushort4 ns = *(const ushort4*)&ssrc[i];
            uint4 n0 = *(const uint4*)&inf[(size_t)ns.x * F];
            uint4 n1 = *(const uint4*)&inf[(size_t)ns.y * F];
            uint4 n2 = *(const uint4*)&inf[(size_t)ns.z * F];
            uint4 n3 = *(const uint4*)&inf[(size_t)ns.w * F];
            DEC_ADD4(c0) DEC_ADD4(c1) DEC_ADD4(c2) DEC_ADD4(c3)
            c0 = n0; c1 = n1; c2 = n2; c3 = n3;
        }
        DEC_ADD4(c0) DEC_ADD4(c1) DEC_ADD4(c2) DEC_ADD4(c3)
    }
    float scl = (d > 0) ? 1.f / (float)d : 0.f;
    uint4 o0, o1;
    o0.x = pack2bf(a[0] * scl, a[1] * scl);
    o0.y = pack2bf(a[2] * scl, a[3] * scl);
    o0.z = pack2bf(a[4] * scl, a[5] * scl);
    o0.w = pack2bf(a[6] * scl, a[7] * scl);
    o1.x = pack2bf(a[8] * scl, a[9] * scl);
    o1.y = pack2bf(a[10] * scl, a[11] * scl);
    o1.z = pack2bf(a[12] * scl, a[13] * scl);
    o1.w = pack2bf(a[14] * scl, a[15] * scl);
    *(uint4*)&out[(size_t)n * ostride + f16] = o0;
    *(uint4*)&out[(size_t)n * ostride + f16 + 8] = o1;
}

// ---------------------------------------------------------------------------
// bf16 MFMA GEMM. A (streamed, 25-50MB) double-buffered in LDS with
// XOR-swizzle; W (tiny, L2-hot) fragments loaded DIRECT from global into
// registers each K-step — halves LDS (64KB -> 35KB) => 4 blocks/CU.
// C[m][coff+n] = op(A[m,:].W[n,:] + bias[n]).  FP8W>0: also emit fp8 copy
// into fp8out via LDS transpose (reuses staging LDS after K-loop).
// ---------------------------------------------------------------------------
template <int KSTEPS, bool RELU, bool BIAS, int FP8W>
__global__ __launch_bounds__(256) void k_gemm_mfma(const unsigned short* __restrict__ A,
                                                   const unsigned short* __restrict__ W,
                                                   const float* __restrict__ bias,
                                                   unsigned short* __restrict__ C,
                                                   int ldc, int coff,
                                                   unsigned char* __restrict__ fp8out,
                                                   int M) {
    constexpr int K = KSTEPS * 64;
    // 17408 shorts = 34816B: bytes 0..32767 = A dbuf (2 x 16KB); transpose
    // phase (after K-loop) uses 128*136 shorts.
    __shared__ unsigned short SH[17408];

    const int tid = threadIdx.x;
    const int lane = tid & 63;
    const int w = tid >> 6;
    const int row0 = blockIdx.x * 128;
    const int colb = blockIdx.y * 128;

    const int srow_b = w * 32 + (lane >> 3);
    const int slot = lane & 7;

    f32x4 acc[4][4];
#pragma unroll
    for (int i = 0; i < 4; ++i)
#pragma unroll
        for (int j = 0; j < 4; ++j) acc[i][j] = (f32x4){0.f, 0.f, 0.f, 0.f};

    const int m0 = (w >> 1) * 64;
    const int n0 = (w & 1) * 64;

    // per-lane W row base pointers (row = colb + n0 + nf*16 + (lane&15),
    // k-phase (lane>>4)*8). Per K-step loads are at + ks*64 + kk*32.
    const unsigned short* wrow[4];
#pragma unroll
    for (int nf = 0; nf < 4; ++nf)
        wrow[nf] = W + (size_t)(colb + n0 + nf * 16 + (lane & 15)) * K + ((lane >> 4) << 3);

    auto STAGE_A = [&](int b, int ks) {
        const int kk0 = ks * 64;
#pragma unroll
        for (int it = 0; it < 4; ++it) {
            int r = srow_b + it * 8;
            int sl = (slot ^ (r & 7)) << 3;
            int ra = min(row0 + r, M - 1);
            load_lds16(A + (size_t)ra * K + kk0 + sl,
                       (char*)SH + b * 16384 + w * 4096 + it * 1024);
        }
    };

    STAGE_A(0, 0);
    __syncthreads();
    int cur = 0;

    for (int ks = 0; ks < KSTEPS; ++ks) {
        if (ks + 1 < KSTEPS) STAGE_A(cur ^ 1, ks + 1);

        // W fragments direct from global (L2-hot)
        bf16x8 bfr[4][2];
#pragma unroll
        for (int nf = 0; nf < 4; ++nf)
#pragma unroll
            for (int kk = 0; kk < 2; ++kk)
                bfr[nf][kk] = *(const bf16x8*)(wrow[nf] + ks * 64 + kk * 32);

        const char* Ab = (const char*)SH + cur * 16384;
        bf16x8 af[4][2];
#pragma unroll
        for (int mf = 0; mf < 4; ++mf)
#pragma unroll
            for (int kk = 0; kk < 2; ++kk) {
                int r = m0 + mf * 16 + (lane & 15);
                int sl = (kk * 4 + (lane >> 4)) ^ (r & 7);
                af[mf][kk] = *(const bf16x8*)(Ab + r * 128 + sl * 16);
            }
#pragma unroll
        for (int mf = 0; mf < 4; ++mf)
#pragma unroll
            for (int nf = 0; nf < 4; ++nf)
#pragma unroll
                for (int kk = 0; kk < 2; ++kk)
                    acc[mf][nf] = __builtin_amdgcn_mfma_f32_16x16x32_bf16(
                        af[mf][kk], bfr[nf][kk], acc[mf][nf], 0, 0, 0);
        __syncthreads();
        cur ^= 1;
    }

    const bool do8 = (FP8W > 0) && (colb < FP8W);

    // epilogue: C/D layout col=lane&15, row=(lane>>4)*4+reg
#pragma unroll
    for (int mf = 0; mf < 4; ++mf) {
#pragma unroll
        for (int nf = 0; nf < 4; ++nf) {
            int cl = n0 + nf * 16 + (lane & 15);
            int c = colb + cl;
            float bv = 0.f;
            if constexpr (BIAS) bv = bias[c];
#pragma unroll
            for (int r = 0; r < 4; ++r) {
                int ml = m0 + mf * 16 + ((lane >> 4) << 2) + r;
                int m = row0 + ml;
                if (m < M) {
                    float v = acc[mf][nf][r] + bv;
                    if constexpr (RELU) v = fmaxf(v, 0.f);
                    unsigned short bf = f2bf(v);
                    C[(size_t)m * ldc + coff + c] = bf;
                    if constexpr (FP8W > 0)
                        if (do8) SH[ml * 136 + cl] = bf;
                }
            }
        }
    }

    if constexpr (FP8W > 0) {
        if (do8) {
            __syncthreads();
#pragma unroll
            for (int q0 = 0; q0 < 1024; q0 += 256) {
                int q = q0 + tid;
                int row = q >> 3;
                int m = row0 + row;
                if (m < M) {
                    int cg = (q & 7) << 4;
                    const unsigned short* tp = SH + row * 136 + cg;
                    uint4 w0 = *(const uint4*)tp;
                    uint4 w1 = *(const uint4*)(tp + 8);
                    uint4 o;
                    o.x = pack4fp8(bf_lo(w0.x), bf_hi(w0.x), bf_lo(w0.y), bf_hi(w0.y));
                    o.y = pack4fp8(bf_lo(w0.z), bf_hi(w0.z), bf_lo(w0.w), bf_hi(w0.w));
                    o.z = pack4fp8(bf_lo(w1.x), bf_hi(w1.x), bf_lo(w1.y), bf_hi(w1.y));
                    o.w = pack4fp8(bf_lo(w1.z), bf_hi(w1.z), bf_lo(w1.w), bf_hi(w1.w));
                    *(uint4*)&fp8out[(size_t)m * FP8W + colb + cg] = o;
                }
            }
        }
    }
}

// ---------------------------------------------------------------------------
// Fused final: pipelined gather (fp8 t3l) + relu(agg3+b3+t3r) + per-graph pool.
// ---------------------------------------------------------------------------
__global__ __launch_bounds__(256) void k_final8(const unsigned char* __restrict__ t3l8,
                                                const unsigned short* __restrict__ t3,
                                                const float* __restrict__ b3,
                                                const int* __restrict__ offs,
                                                const unsigned short* __restrict__ deg,
                                                const unsigned short* __restrict__ ssrc,
                                                const int* __restrict__ batch,
                                                float* __restrict__ out) {
    __shared__ float sm[16][128];
    __shared__ int bsh[16];
    const int t = threadIdx.x;
    const int sub = t >> 4;
    const int f8 = (t & 15) * 8;
    const int n = blockIdx.x * 16 + sub;

    int s0 = offs[n];
    int d = deg[n];
    int pd = (d + 3) & ~3;
    float a[8];
#pragma unroll
    for (int j = 0; j < 8; ++j) a[j] = 0.f;
    const unsigned char* inf = t3l8 + f8;
    if (pd > 0) {
        ushort4 es = *(const ushort4*)&ssrc[s0];
        uint2 c0 = *(const uint2*)&inf[(size_t)es.x * 128];
        uint2 c1 = *(const uint2*)&inf[(size_t)es.y * 128];
        uint2 c2 = *(const uint2*)&inf[(size_t)es.z * 128];
        uint2 c3 = *(const uint2*)&inf[(size_t)es.w * 128];
        for (int i = s0 + 4; i < s0 + pd; i += 4) {
            ushort4 ns = *(const ushort4*)&ssrc[i];
            uint2 n0 = *(const uint2*)&inf[(size_t)ns.x * 128];
            uint2 n1 = *(const uint2*)&inf[(size_t)ns.y * 128];
            uint2 n2 = *(const uint2*)&inf[(size_t)ns.z * 128];
            uint2 n3 = *(const uint2*)&inf[(size_t)ns.w * 128];
            DEC_ADD(c0.x, 0) DEC_ADD(c0.y, 4)
            DEC_ADD(c1.x, 0) DEC_ADD(c1.y, 4)
            DEC_ADD(c2.x, 0) DEC_ADD(c2.y, 4)
            DEC_ADD(c3.x, 0) DEC_ADD(c3.y, 4)
            c0 = n0; c1 = n1; c2 = n2; c3 = n3;
        }
        DEC_ADD(c0.x, 0) DEC_ADD(c0.y, 4)
        DEC_ADD(c1.x, 0) DEC_ADD(c1.y, 4)
        DEC_ADD(c2.x, 0) DEC_ADD(c2.y, 4)
        DEC_ADD(c3.x, 0) DEC_ADD(c3.y, 4)
    }
    float scl = (d > 0) ? 1.f / (float)d : 0.f;
    float4 bv0 = *(const float4*)&b3[f8];
    float4 bv1 = *(const float4*)&b3[f8 + 4];
    uint4 tr = *(const uint4*)&t3[(size_t)n * 256 + 128 + f8];
    float tv[8] = {bf_lo(tr.x), bf_hi(tr.x), bf_lo(tr.y), bf_hi(tr.y),
                   bf_lo(tr.z), bf_hi(tr.z), bf_lo(tr.w), bf_hi(tr.w)};
    float bb[8] = {bv0.x, bv0.y, bv0.z, bv0.w, bv1.x, bv1.y, bv1.z, bv1.w};
#pragma unroll
    for (int j = 0; j < 8; ++j)
        sm[sub][f8 + j] = fmaxf(a[j] * scl + bb[j] + tv[j], 0.f);
    if ((t & 15) == 0) bsh[sub] = batch[n];
    __syncthreads();

    if (t < 128) {
        float local = 0.f;
        int cur = -1;
#pragma unroll
        for (int k = 0; k < 16; ++k) {
            int b = bsh[k];
            if (b != cur) {
                if (cur >= 0) atomicAdd(&out[(size_t)cur * 128 + t], local);
                local = 0.f;
                cur = b;
            }
            local += sm[k][t];
        }
        if (cur >= 0) atomicAdd(&out[(size_t)cur * 128 + t], local);
    }
}

// ---------------------------------------------------------------------------
extern "C" void kernel_launch(void* const* d_in, const int* in_sizes, int n_in,
                              void* d_out, int out_size, void* d_ws, size_t ws_size,
                              hipStream_t stream) {
    const float* x   = (const float*)d_in[0];
    const int* ei    = (const int*)d_in[1];
    const int* batch = (const int*)d_in[2];
    const float* W1l = (const float*)d_in[3];
    const float* b1  = (const float*)d_in[4];
    const float* W1r = (const float*)d_in[5];
    const float* W2l = (const float*)d_in[6];
    const float* b2  = (const float*)d_in[7];
    const float* W2r = (const float*)d_in[8];
    const float* W3l = (const float*)d_in[9];
    const float* b3  = (const float*)d_in[10];
    const float* W3r = (const float*)d_in[11];
    const int* src = ei;
    const int* dst = ei + N_EDGES;
    float* out = (float*)d_out;

    size_t off = 0;
    auto carve = [&](size_t bytes) {
        void* p = (char*)d_ws + off;
        off += (bytes + 255) & ~(size_t)255;
        return p;
    };
    int* gcnt   = (int*)carve(256 * 4);
    int* offs   = (int*)carve((size_t)N_NODES * 4);
    unsigned short* deg  = (unsigned short*)carve((size_t)N_NODES * 2);
    unsigned short* ssrc = (unsigned short*)carve((size_t)(N_EDGES + NBKT * 1024) * 2);
    unsigned short* A1   = (unsigned short*)carve((size_t)N_NODES * 256 * 2);  // [agg1|x]
    unsigned short* A2   = (unsigned short*)carve((size_t)N_NODES * 512 * 2);  // [agg2|h1]
    unsigned short* A3   = (unsigned short*)carve((size_t)N_NODES * 256 * 2);  // h2
    // t3 region doubles as bucketed edge staging (dead before gemm3 writes t3)
    void* t3region = carve((size_t)N_NODES * 256 * 2);  // 25.6MB >= 250*7168*4
    unsigned int* bucketed = (unsigned int*)t3region;
    unsigned short* t3 = (unsigned short*)t3region;
    unsigned char* x8   = (unsigned char*)carve((size_t)(N_NODES + 1) * 128);
    unsigned char* h18  = (unsigned char*)carve((size_t)(N_NODES + 1) * 256);
    unsigned char* t3l8 = (unsigned char*)carve((size_t)(N_NODES + 1) * 128);
    unsigned short* Wp1 = (unsigned short*)carve((size_t)256 * 256 * 2);
    unsigned short* Wp2 = (unsigned short*)carve((size_t)256 * 512 * 2);
    unsigned short* Wp3 = (unsigned short*)carve((size_t)256 * 256 * 2);

    hipMemsetAsync(gcnt, 0, 256 * 4, stream);
    hipMemsetAsync(d_out, 0, (size_t)out_size * 4, stream);

    // CSR build + converts (+ zero rows)
    k_front<<<NBB + NCVX + NCVW, 256, 0, stream>>>(src, dst, bucketed, gcnt,
                                                   x, A1 + 128, x8, h18, t3l8,
                                                   W1l, W1r, W2l, W2r, W3l, W3r,
                                                   Wp1, Wp2, Wp3);
    k_place<<<NBKT, 512, 0, stream>>>(bucketed, gcnt, offs, deg, ssrc);

    const dim3 ggrid((N_NODES + 127) / 128, 2);

    // L1: agg1 = mean(x8[src]); h1 = relu([agg1|x]@Wp1^T+b1) -> A2 right + h18 fp8
    k_gather8<128><<<(N_NODES + 31) / 32, 256, 0, stream>>>(x8, A1, 256, offs, deg, ssrc);
    k_gemm_mfma<4, true, true, 256><<<ggrid, 256, 0, stream>>>(A1, Wp1, b1, A2, 512, 256, h18, N_NODES);

    // L2: agg2 = mean(h18[src]); h2 = relu([agg2|h1]@Wp2^T+b2) -> A3
    k_gather8<256><<<(N_NODES + 15) / 16, 256, 0, stream>>>(h18, A2, 512, offs, deg, ssrc);
    k_gemm_mfma<8, true, true, 0><<<ggrid, 256, 0, stream>>>(A2, Wp2, b2, A3, 256, 0, nullptr, N_NODES);

    // L3: t3 = h2 @ [W3l;W3r]^T (left half also as fp8 t3l8); fused gather+pool
    k_gemm_mfma<4, false, false, 128><<<ggrid, 256, 0, stream>>>(A3, Wp3, nullptr, t3, 256, 0, t3l8, N_NODES);
    k_final8<<<N_NODES / 16, 256, 0, stream>>>(t3l8, t3, b3, offs, deg, ssrc, batch, out);
}

// Round 13
// 305.853 us; speedup vs baseline: 1.1450x; 1.1450x over previous
//
#include <hip/hip_runtime.h>
#include <hip/hip_bf16.h>

#define N_NODES 50000
#define N_EDGES 1600000
#define N_GRAPHS 64

// bucket sort geometry
#define NBKT 250          // buckets of 200 nodes each
#define BKT_NODES 200
#define BKT_CAP 7168      // mean 6400, sigma ~80; +9.6 sigma; guard-checked
#define CHUNK 4096        // edges per k_front bucket block
#define NBB 391           // ceil(1600000/4096)
#define NCVX 6250         // x-convert blocks
#define NCVW 256          // weight-convert blocks
#define ZROW N_NODES      // zero-row index for gather padding

typedef short bf16x8 __attribute__((ext_vector_type(8)));
typedef float f32x4 __attribute__((ext_vector_type(4)));
typedef float f32x2 __attribute__((ext_vector_type(2)));

__device__ __forceinline__ float bf_lo(unsigned int u) { return __uint_as_float(u << 16); }
__device__ __forceinline__ float bf_hi(unsigned int u) { return __uint_as_float(u & 0xffff0000u); }
__device__ __forceinline__ unsigned short f2bf(float f) {
    unsigned int u = __float_as_uint(f);
    u = (u + 0x7fffu + ((u >> 16) & 1u)) >> 16;
    return (unsigned short)u;
}
__device__ __forceinline__ unsigned int pack2bf(float a, float b) {
    return (unsigned int)f2bf(a) | ((unsigned int)f2bf(b) << 16);
}
__device__ __forceinline__ unsigned int pack4fp8(float a, float b, float c, float d) {
    unsigned int q = __builtin_amdgcn_cvt_pk_fp8_f32(a, b, 0, false);
    q = __builtin_amdgcn_cvt_pk_fp8_f32(c, d, q, true);
    return q;
}
__device__ __forceinline__ void load_lds16(const void* g, void* l) {
    __builtin_amdgcn_global_load_lds(
        (const __attribute__((address_space(1))) void*)g,
        (__attribute__((address_space(3))) void*)l, 16, 0, 0);
}

// ---------------------------------------------------------------------------
// k_front: fused {edge bucketing | x->bf16+fp8 convert | weight converts}
// First convert block also writes the ZROW zero rows (replaces 3 memsets).
// ---------------------------------------------------------------------------
__global__ __launch_bounds__(256) void k_front(
    const int* __restrict__ src, const int* __restrict__ dst,
    unsigned int* __restrict__ bucketed, int* __restrict__ gcnt,
    const float* __restrict__ x, unsigned short* __restrict__ A1x,
    unsigned char* __restrict__ x8, unsigned char* __restrict__ h18,
    unsigned char* __restrict__ t3l8,
    const float* __restrict__ W1l, const float* __restrict__ W1r,
    const float* __restrict__ W2l, const float* __restrict__ W2r,
    const float* __restrict__ W3l, const float* __restrict__ W3r,
    unsigned short* __restrict__ Wp1, unsigned short* __restrict__ Wp2,
    unsigned short* __restrict__ Wp3) {
    const int blk = blockIdx.x;
    const int t = threadIdx.x;

    if (blk < NBB) {
        __shared__ int lcnt[256];
        __shared__ int sc[256];
        __shared__ int lscan[256];
        __shared__ int gb[256];
        __shared__ unsigned int grouped[CHUNK];

        const int base = blk * CHUNK;
        const int ccnt = min(CHUNK, N_EDGES - base);
        lcnt[t] = 0;
        __syncthreads();

        unsigned int pk[CHUNK / 256];
        int rk[CHUNK / 256];
#pragma unroll
        for (int r = 0; r < CHUNK / 256; ++r) {
            int j = r * 256 + t;
            rk[r] = -1;
            if (j < ccnt) {
                int i = base + j;
                int s = src[i];
                int d = dst[i];
                int b = d / BKT_NODES;
                int dl = d - b * BKT_NODES;
                pk[r] = (unsigned int)s | ((unsigned int)dl << 16) | ((unsigned int)b << 24);
                rk[r] = atomicAdd(&lcnt[b], 1);
            }
        }
        __syncthreads();
        sc[t] = lcnt[t];
        __syncthreads();
        for (int off = 1; off < 256; off <<= 1) {
            int v = (t >= off) ? sc[t - off] : 0;
            __syncthreads();
            sc[t] += v;
            __syncthreads();
        }
        lscan[t] = sc[t] - lcnt[t];
        if (t < NBKT && lcnt[t] > 0) gb[t] = atomicAdd(&gcnt[t], lcnt[t]);
        __syncthreads();
#pragma unroll
        for (int r = 0; r < CHUNK / 256; ++r) {
            if (rk[r] >= 0) {
                int b = pk[r] >> 24;
                grouped[lscan[b] + rk[r]] = pk[r];
            }
        }
        __syncthreads();
#pragma unroll
        for (int r = 0; r < CHUNK / 256; ++r) {
            int j = r * 256 + t;
            if (j < ccnt) {
                unsigned int v = grouped[j];
                int b = v >> 24;
                int pos = gb[b] + (j - lscan[b]);
                if (pos < BKT_CAP) bucketed[b * BKT_CAP + pos] = v;
            }
        }
    } else if (blk < NBB + NCVX) {
        // ---- x -> bf16 (A1 right half, stride 256) + fp8 ([.][128]) ----
        int i = (blk - NBB) * 256 + t;  // exactly 1.6M units of 4 floats
        int r = i >> 5;
        int f4 = (i & 31) << 2;
        float4 v = *(const float4*)&x[(size_t)r * 128 + f4];
        uint2 o;
        o.x = pack2bf(v.x, v.y);
        o.y = pack2bf(v.z, v.w);
        *(uint2*)&A1x[(size_t)r * 256 + f4] = o;
        *(unsigned int*)&x8[(size_t)r * 128 + f4] = pack4fp8(v.x, v.y, v.z, v.w);
        // zero rows for gather padding (once)
        if (blk == NBB && t < 32) {
            uint4 z = make_uint4(0, 0, 0, 0);
            if (t < 8) *(uint4*)&x8[(size_t)ZROW * 128 + t * 16] = z;
            else if (t < 24) *(uint4*)&h18[(size_t)ZROW * 256 + (t - 8) * 16] = z;
            else *(uint4*)&t3l8[(size_t)ZROW * 128 + (t - 24) * 16] = z;
        }
    } else {
        // ---- all 6 weight matrices -> packed bf16 ----
        int i = (blk - NBB - NCVX) * 256 + t;  // 0..65535
        const float* srcp;
        unsigned short* dstp;
        int sf4, dstride;
        if (i < 16384) {
            int h = i >> 13;
            i &= 8191;
            srcp = h ? W1r : W1l;
            dstp = Wp1 + (h ? 128 : 0);
            sf4 = 32; dstride = 256;
        } else if (i < 49152) {
            int j = i - 16384;
            int h = j >> 14;
            i = j & 16383;
            srcp = h ? W2r : W2l;
            dstp = Wp2 + (h ? 256 : 0);
            sf4 = 64; dstride = 512;
        } else {
            int j = i - 49152;
            int h = j >> 13;
            i = j & 8191;
            srcp = h ? W3r : W3l;
            dstp = Wp3 + (h ? 128 * 256 : 0);
            sf4 = 64; dstride = 256;
        }
        int r = i / sf4;
        int f4 = (i % sf4) * 4;
        float4 v = *(const float4*)&srcp[(size_t)r * (sf4 * 4) + f4];
        uint2 o;
        o.x = pack2bf(v.x, v.y);
        o.y = pack2bf(v.z, v.w);
        *(uint2*)&dstp[(size_t)r * dstride + f4] = o;
    }
}

// ---------------------------------------------------------------------------
// k_place: one block (512 thr) per bucket. Slack-scan (x4-rounded) of bucket
// counts -> x4-aligned global starts; LDS counting sort -> offs/deg + padded
// ssrc (segments padded to x4 with ZROW).
// ---------------------------------------------------------------------------
__global__ __launch_bounds__(512) void k_place(const unsigned int* __restrict__ bucketed,
                                               const int* __restrict__ gcnt,
                                               int* __restrict__ offs,
                                               unsigned short* __restrict__ deg,
                                               unsigned short* __restrict__ ssrc) {
    __shared__ unsigned int ent[BKT_CAP];
    __shared__ unsigned short rks[BKT_CAP];
    __shared__ int lcnt[256];
    __shared__ int sc[256];
    __shared__ int lofs[256];
    __shared__ int gs;

    const int b = blockIdx.x;
    const int t = threadIdx.x;

    // slack scan (inclusive) over x4-rounded per-bucket upper bounds
    if (t < 256) sc[t] = (t < NBKT) ? (((gcnt[t] + 3) & ~3) + 3 * BKT_NODES) : 0;
    __syncthreads();
    for (int off = 1; off < 256; off <<= 1) {
        int u = 0;
        if (t < 256 && t >= off) u = sc[t - off];
        __syncthreads();
        if (t < 256) sc[t] += u;
        __syncthreads();
    }
    if (t == 0) gs = (b == 0) ? 0 : sc[b - 1];
    if (t < 256) lcnt[t] = 0;
    __syncthreads();

    const int cnt = min(gcnt[b], BKT_CAP);
    const unsigned int* eg = bucketed + (size_t)b * BKT_CAP;
    for (int i = t; i < cnt; i += 512) {
        unsigned int v = eg[i];
        ent[i] = v;
        int dl = (v >> 16) & 0xFF;
        rks[i] = (unsigned short)atomicAdd(&lcnt[dl], 1);
    }
    __syncthreads();
    // padded exclusive scan of per-node counts
    int pc = 0;
    if (t < 256) {
        pc = (lcnt[t] + 3) & ~3;
        sc[t] = pc;
    }
    __syncthreads();
    for (int off = 1; off < 256; off <<= 1) {
        int u = 0;
        if (t < 256 && t >= off) u = sc[t - off];
        __syncthreads();
        if (t < 256) sc[t] += u;
        __syncthreads();
    }
    if (t < 256) lofs[t] = sc[t] - pc;
    __syncthreads();
    const int gstart = gs;
    if (t < BKT_NODES) {
        offs[b * BKT_NODES + t] = gstart + lofs[t];
        deg[b * BKT_NODES + t] = (unsigned short)lcnt[t];
    }
    for (int i = t; i < cnt; i += 512) {
        unsigned int v = ent[i];
        int dl = (v >> 16) & 0xFF;
        ssrc[gstart + lofs[dl] + (int)rks[i]] = (unsigned short)(v & 0xFFFF);
    }
    if (t < BKT_NODES) {
        int d = lcnt[t], pd = (d + 3) & ~3;
        int base = gstart + lofs[t];
        for (int j = d; j < pd; ++j) ssrc[base + j] = (unsigned short)ZROW;
    }
}

// ---------------------------------------------------------------------------
// fp8 gather-mean -> bf16. Padded x4 segments, x4-aligned starts, 2-deep
// register pipeline.
// ---------------------------------------------------------------------------
#define DEC_ADD(dw, base)                                             \
    {                                                                 \
        f32x2 lo_ = __builtin_amdgcn_cvt_pk_f32_fp8((dw), false);     \
        f32x2 hi_ = __builtin_amdgcn_cvt_pk_f32_fp8((dw), true);      \
        a[(base) + 0] += lo_.x;                                       \
        a[(base) + 1] += lo_.y;                                       \
        a[(base) + 2] += hi_.x;                                       \
        a[(base) + 3] += hi_.y;                                       \
    }
#define DEC_ADD4(v) { DEC_ADD((v).x, 0) DEC_ADD((v).y, 4) DEC_ADD((v).z, 8) DEC_ADD((v).w, 12) }

template <int F>
__global__ __launch_bounds__(256) void k_gather8(const unsigned char* __restrict__ in,
                                                 unsigned short* __restrict__ out,
                                                 int ostride,
                                                 const int* __restrict__ offs,
                                                 const unsigned short* __restrict__ deg,
                                                 const unsigned short* __restrict__ ssrc) {
    constexpr int TPN = F / 16;
    constexpr int NPB = 256 / TPN;
    int n = blockIdx.x * NPB + threadIdx.x / TPN;
    int f16 = (threadIdx.x % TPN) * 16;
    if (n >= N_NODES) return;
    int s0 = offs[n];
    int d = deg[n];
    int pd = (d + 3) & ~3;
    float a[16];
#pragma unroll
    for (int j = 0; j < 16; ++j) a[j] = 0.f;
    const unsigned char* inf = in + f16;
    if (pd > 0) {
        ushort4 es = *(const ushort4*)&ssrc[s0];
        uint4 c0 = *(const uint4*)&inf[(size_t)es.x * F];
        uint4 c1 = *(const uint4*)&inf[(size_t)es.y * F];
        uint4 c2 = *(const uint4*)&inf[(size_t)es.z * F];
        uint4 c3 = *(const uint4*)&inf[(size_t)es.w * F];
        for (int i = s0 + 4; i < s0 + pd; i += 4) {
            ushort4 ns = *(const ushort4*)&ssrc[i];
            uint4 n0 = *(const uint4*)&inf[(size_t)ns.x * F];
            uint4 n1 = *(const uint4*)&inf[(size_t)ns.y * F];
            uint4 n2 = *(const uint4*)&inf[(size_t)ns.z * F];
            uint4 n3 = *(const uint4*)&inf[(size_t)ns.w * F];
            DEC_ADD4(c0) DEC_ADD4(c1) DEC_ADD4(c2) DEC_ADD4(c3)
            c0 = n0; c1 = n1; c2 = n2; c3 = n3;
        }
        DEC_ADD4(c0) DEC_ADD4(c1) DEC_ADD4(c2) DEC_ADD4(c3)
    }
    float scl = (d > 0) ? 1.f / (float)d : 0.f;
    uint4 o0, o1;
    o0.x = pack2bf(a[0] * scl, a[1] * scl);
    o0.y = pack2bf(a[2] * scl, a[3] * scl);
    o0.z = pack2bf(a[4] * scl, a[5] * scl);
    o0.w = pack2bf(a[6] * scl, a[7] * scl);
    o1.x = pack2bf(a[8] * scl, a[9] * scl);
    o1.y = pack2bf(a[10] * scl, a[11] * scl);
    o1.z = pack2bf(a[12] * scl, a[13] * scl);
    o1.w = pack2bf(a[14] * scl, a[15] * scl);
    *(uint4*)&out[(size_t)n * ostride + f16] = o0;
    *(uint4*)&out[(size_t)n * ostride + f16 + 8] = o1;
}

// ---------------------------------------------------------------------------
// bf16 MFMA GEMM, latency-optimized for skinny shapes: BM=64, BN=128,
// single-buffered LDS (A 8KB + W 16KB = 24KB -> 6 blocks/CU), 4 waves each
// computing 32x64. XOR-swizzle both-sides. C[m][coff+n] = op(A.W^T + bias).
// FP8W>0: also emit fp8 copy via LDS transpose (reuses staging LDS).
// ---------------------------------------------------------------------------
template <int KSTEPS, bool RELU, bool BIAS, int FP8W>
__global__ __launch_bounds__(256) void k_gemm_mfma(const unsigned short* __restrict__ A,
                                                   const unsigned short* __restrict__ W,
                                                   const float* __restrict__ bias,
                                                   unsigned short* __restrict__ C,
                                                   int ldc, int coff,
                                                   unsigned char* __restrict__ fp8out,
                                                   int M) {
    constexpr int K = KSTEPS * 64;
    // 24KB: bytes [0,8192) = A tile 64x64; [8192,24576) = W tile 128x64.
    // fp8-transpose phase (after K-loop) reuses as [64][136] shorts (17.4KB).
    __shared__ unsigned short SH[12288];

    const int tid = threadIdx.x;
    const int lane = tid & 63;
    const int w = tid >> 6;
    const int row0 = blockIdx.x * 64;
    const int colb = blockIdx.y * 128;

    const int slot = lane & 7;

    f32x4 acc[2][4];
#pragma unroll
    for (int i = 0; i < 2; ++i)
#pragma unroll
        for (int j = 0; j < 4; ++j) acc[i][j] = (f32x4){0.f, 0.f, 0.f, 0.f};

    const int m0 = (w >> 1) * 32;
    const int n0 = (w & 1) * 64;

    for (int ks = 0; ks < KSTEPS; ++ks) {
        const int kk0 = ks * 64;
        // stage A (64x64): 2 wave-writes/wave
#pragma unroll
        for (int it = 0; it < 2; ++it) {
            int r = w * 16 + it * 8 + (lane >> 3);
            int sl = (slot ^ (r & 7)) << 3;
            int ra = min(row0 + r, M - 1);
            load_lds16(A + (size_t)ra * K + kk0 + sl,
                       (char*)SH + w * 2048 + it * 1024);
        }
        // stage W (128x64): 4 wave-writes/wave
#pragma unroll
        for (int it = 0; it < 4; ++it) {
            int r = w * 32 + it * 8 + (lane >> 3);
            int sl = (slot ^ (r & 7)) << 3;
            load_lds16(W + (size_t)(colb + r) * K + kk0 + sl,
                       (char*)SH + 8192 + w * 4096 + it * 1024);
        }
        __syncthreads();  // drains global_load_lds (vmcnt) + all waves staged

        bf16x8 af[2][2], bfr[4][2];
#pragma unroll
        for (int mf = 0; mf < 2; ++mf)
#pragma unroll
            for (int kk = 0; kk < 2; ++kk) {
                int r = m0 + mf * 16 + (lane & 15);
                int sl = (kk * 4 + (lane >> 4)) ^ (r & 7);
                af[mf][kk] = *(const bf16x8*)((const char*)SH + r * 128 + sl * 16);
            }
#pragma unroll
        for (int nf = 0; nf < 4; ++nf)
#pragma unroll
            for (int kk = 0; kk < 2; ++kk) {
                int r = n0 + nf * 16 + (lane & 15);
                int sl = (kk * 4 + (lane >> 4)) ^ (r & 7);
                bfr[nf][kk] = *(const bf16x8*)((const char*)SH + 8192 + r * 128 + sl * 16);
            }
#pragma unroll
        for (int mf = 0; mf < 2; ++mf)
#pragma unroll
            for (int nf = 0; nf < 4; ++nf)
#pragma unroll
                for (int kk = 0; kk < 2; ++kk)
                    acc[mf][nf] = __builtin_amdgcn_mfma_f32_16x16x32_bf16(
                        af[mf][kk], bfr[nf][kk], acc[mf][nf], 0, 0, 0);
        __syncthreads();  // all reads done before next-step overwrite
    }

    const bool do8 = (FP8W > 0) && (colb < FP8W);

    // epilogue: C/D layout col=lane&15, row=(lane>>4)*4+reg
#pragma unroll
    for (int mf = 0; mf < 2; ++mf) {
#pragma unroll
        for (int nf = 0; nf < 4; ++nf) {
            int cl = n0 + nf * 16 + (lane & 15);
            int c = colb + cl;
            float bv = 0.f;
            if constexpr (BIAS) bv = bias[c];
#pragma unroll
            for (int r = 0; r < 4; ++r) {
                int ml = m0 + mf * 16 + ((lane >> 4) << 2) + r;
                int m = row0 + ml;
                if (m < M) {
                    float v = acc[mf][nf][r] + bv;
                    if constexpr (RELU) v = fmaxf(v, 0.f);
                    unsigned short bf = f2bf(v);
                    C[(size_t)m * ldc + coff + c] = bf;
                    if constexpr (FP8W > 0)
                        if (do8) SH[ml * 136 + cl] = bf;
                }
            }
        }
    }

    if constexpr (FP8W > 0) {
        if (do8) {
            __syncthreads();
#pragma unroll
            for (int q0 = 0; q0 < 512; q0 += 256) {
                int q = q0 + tid;
                int row = q >> 3;
                int m = row0 + row;
                if (m < M) {
                    int cg = (q & 7) << 4;
                    const unsigned short* tp = SH + row * 136 + cg;
                    uint4 w0 = *(const uint4*)tp;
                    uint4 w1 = *(const uint4*)(tp + 8);
                    uint4 o;
                    o.x = pack4fp8(bf_lo(w0.x), bf_hi(w0.x), bf_lo(w0.y), bf_hi(w0.y));
                    o.y = pack4fp8(bf_lo(w0.z), bf_hi(w0.z), bf_lo(w0.w), bf_hi(w0.w));
                    o.z = pack4fp8(bf_lo(w1.x), bf_hi(w1.x), bf_lo(w1.y), bf_hi(w1.y));
                    o.w = pack4fp8(bf_lo(w1.z), bf_hi(w1.z), bf_lo(w1.w), bf_hi(w1.w));
                    *(uint4*)&fp8out[(size_t)m * FP8W + colb + cg] = o;
                }
            }
        }
    }
}

// ---------------------------------------------------------------------------
// Fused final: pipelined gather (fp8 t3l) + relu(agg3+b3+t3r) + per-graph pool.
// ---------------------------------------------------------------------------
__global__ __launch_bounds__(256) void k_final8(const unsigned char* __restrict__ t3l8,
                                                const unsigned short* __restrict__ t3,
                                                const float* __restrict__ b3,
                                                const int* __restrict__ offs,
                                                const unsigned short* __restrict__ deg,
                                                const unsigned short* __restrict__ ssrc,
                                                const int* __restrict__ batch,
                                                float* __restrict__ out) {
    __shared__ float sm[16][128];
    __shared__ int bsh[16];
    const int t = threadIdx.x;
    const int sub = t >> 4;
    const int f8 = (t & 15) * 8;
    const int n = blockIdx.x * 16 + sub;

    int s0 = offs[n];
    int d = deg[n];
    int pd = (d + 3) & ~3;
    float a[8];
#pragma unroll
    for (int j = 0; j < 8; ++j) a[j] = 0.f;
    const unsigned char* inf = t3l8 + f8;
    if (pd > 0) {
        ushort4 es = *(const ushort4*)&ssrc[s0];
        uint2 c0 = *(const uint2*)&inf[(size_t)es.x * 128];
        uint2 c1 = *(const uint2*)&inf[(size_t)es.y * 128];
        uint2 c2 = *(const uint2*)&inf[(size_t)es.z * 128];
        uint2 c3 = *(const uint2*)&inf[(size_t)es.w * 128];
        for (int i = s0 + 4; i < s0 + pd; i += 4) {
            ushort4 ns = *(const ushort4*)&ssrc[i];
            uint2 n0 = *(const uint2*)&inf[(size_t)ns.x * 128];
            uint2 n1 = *(const uint2*)&inf[(size_t)ns.y * 128];
            uint2 n2 = *(const uint2*)&inf[(size_t)ns.z * 128];
            uint2 n3 = *(const uint2*)&inf[(size_t)ns.w * 128];
            DEC_ADD(c0.x, 0) DEC_ADD(c0.y, 4)
            DEC_ADD(c1.x, 0) DEC_ADD(c1.y, 4)
            DEC_ADD(c2.x, 0) DEC_ADD(c2.y, 4)
            DEC_ADD(c3.x, 0) DEC_ADD(c3.y, 4)
            c0 = n0; c1 = n1; c2 = n2; c3 = n3;
        }
        DEC_ADD(c0.x, 0) DEC_ADD(c0.y, 4)
        DEC_ADD(c1.x, 0) DEC_ADD(c1.y, 4)
        DEC_ADD(c2.x, 0) DEC_ADD(c2.y, 4)
        DEC_ADD(c3.x, 0) DEC_ADD(c3.y, 4)
    }
    float scl = (d > 0) ? 1.f / (float)d : 0.f;
    float4 bv0 = *(const float4*)&b3[f8];
    float4 bv1 = *(const float4*)&b3[f8 + 4];
    uint4 tr = *(const uint4*)&t3[(size_t)n * 256 + 128 + f8];
    float tv[8] = {bf_lo(tr.x), bf_hi(tr.x), bf_lo(tr.y), bf_hi(tr.y),
                   bf_lo(tr.z), bf_hi(tr.z), bf_lo(tr.w), bf_hi(tr.w)};
    float bb[8] = {bv0.x, bv0.y, bv0.z, bv0.w, bv1.x, bv1.y, bv1.z, bv1.w};
#pragma unroll
    for (int j = 0; j < 8; ++j)
        sm[sub][f8 + j] = fmaxf(a[j] * scl + bb[j] + tv[j], 0.f);
    if ((t & 15) == 0) bsh[sub] = batch[n];
    __syncthreads();

    if (t < 128) {
        float local = 0.f;
        int cur = -1;
#pragma unroll
        for (int k = 0; k < 16; ++k) {
            int b = bsh[k];
            if (b != cur) {
                if (cur >= 0) atomicAdd(&out[(size_t)cur * 128 + t], local);
                local = 0.f;
                cur = b;
            }
            local += sm[k][t];
        }
        if (cur >= 0) atomicAdd(&out[(size_t)cur * 128 + t], local);
    }
}

// ---------------------------------------------------------------------------
extern "C" void kernel_launch(void* const* d_in, const int* in_sizes, int n_in,
                              void* d_out, int out_size, void* d_ws, size_t ws_size,
                              hipStream_t stream) {
    const float* x   = (const float*)d_in[0];
    const int* ei    = (const int*)d_in[1];
    const int* batch = (const int*)d_in[2];
    const float* W1l = (const float*)d_in[3];
    const float* b1  = (const float*)d_in[4];
    const float* W1r = (const float*)d_in[5];
    const float* W2l = (const float*)d_in[6];
    const float* b2  = (const float*)d_in[7];
    const float* W2r = (const float*)d_in[8];
    const float* W3l = (const float*)d_in[9];
    const float* b3  = (const float*)d_in[10];
    const float* W3r = (const float*)d_in[11];
    const int* src = ei;
    const int* dst = ei + N_EDGES;
    float* out = (float*)d_out;

    size_t off = 0;
    auto carve = [&](size_t bytes) {
        void* p = (char*)d_ws + off;
        off += (bytes + 255) & ~(size_t)255;
        return p;
    };
    int* gcnt   = (int*)carve(256 * 4);
    int* offs   = (int*)carve((size_t)N_NODES * 4);
    unsigned short* deg  = (unsigned short*)carve((size_t)N_NODES * 2);
    unsigned short* ssrc = (unsigned short*)carve((size_t)(N_EDGES + NBKT * 1024) * 2);
    unsigned short* A1   = (unsigned short*)carve((size_t)N_NODES * 256 * 2);  // [agg1|x]
    unsigned short* A2   = (unsigned short*)carve((size_t)N_NODES * 512 * 2);  // [agg2|h1]
    unsigned short* A3   = (unsigned short*)carve((size_t)N_NODES * 256 * 2);  // h2
    // t3 region doubles as bucketed edge staging (dead before gemm3 writes t3)
    void* t3region = carve((size_t)N_NODES * 256 * 2);  // 25.6MB >= 250*7168*4
    unsigned int* bucketed = (unsigned int*)t3region;
    unsigned short* t3 = (unsigned short*)t3region;
    unsigned char* x8   = (unsigned char*)carve((size_t)(N_NODES + 1) * 128);
    unsigned char* h18  = (unsigned char*)carve((size_t)(N_NODES + 1) * 256);
    unsigned char* t3l8 = (unsigned char*)carve((size_t)(N_NODES + 1) * 128);
    unsigned short* Wp1 = (unsigned short*)carve((size_t)256 * 256 * 2);
    unsigned short* Wp2 = (unsigned short*)carve((size_t)256 * 512 * 2);
    unsigned short* Wp3 = (unsigned short*)carve((size_t)256 * 256 * 2);

    hipMemsetAsync(gcnt, 0, 256 * 4, stream);
    hipMemsetAsync(d_out, 0, (size_t)out_size * 4, stream);

    // CSR build + converts (+ zero rows)
    k_front<<<NBB + NCVX + NCVW, 256, 0, stream>>>(src, dst, bucketed, gcnt,
                                                   x, A1 + 128, x8, h18, t3l8,
                                                   W1l, W1r, W2l, W2r, W3l, W3r,
                                                   Wp1, Wp2, Wp3);
    k_place<<<NBKT, 512, 0, stream>>>(bucketed, gcnt, offs, deg, ssrc);

    const dim3 ggrid((N_NODES + 63) / 64, 2);

    // L1: agg1 = mean(x8[src]); h1 = relu([agg1|x]@Wp1^T+b1) -> A2 right + h18 fp8
    k_gather8<128><<<(N_NODES + 31) / 32, 256, 0, stream>>>(x8, A1, 256, offs, deg, ssrc);
    k_gemm_mfma<4, true, true, 256><<<ggrid, 256, 0, stream>>>(A1, Wp1, b1, A2, 512, 256, h18, N_NODES);

    // L2: agg2 = mean(h18[src]); h2 = relu([agg2|h1]@Wp2^T+b2) -> A3
    k_gather8<256><<<(N_NODES + 15) / 16, 256, 0, stream>>>(h18, A2, 512, offs, deg, ssrc);
    k_gemm_mfma<8, true, true, 0><<<ggrid, 256, 0, stream>>>(A2, Wp2, b2, A3, 256, 0, nullptr, N_NODES);

    // L3: t3 = h2 @ [W3l;W3r]^T (left half also as fp8 t3l8); fused gather+pool
    k_gemm_mfma<4, false, false, 128><<<ggrid, 256, 0, stream>>>(A3, Wp3, nullptr, t3, 256, 0, t3l8, N_NODES);
    k_final8<<<N_NODES / 16, 256, 0, stream>>>(t3l8, t3, b3, offs, deg, ssrc, batch, out);
}